// Round 6
// baseline (229.748 us; speedup 1.0000x reference)
//
#include <hip/hip_runtime.h>
#include <hip/hip_bf16.h>

// Problem constants (SparseEmbeddingHead): B=32, S=512, H=1024, V=250002
#define BB 32
#define SS 512
#define HH 1024
#define VV 250002
#define TOKENS (BB * SS)          // 16384
#define OUT_FLOATS (BB * VV)      // 8000064 (divisible by 4)

#define D_BLOCKS 2048
#define D_THREADS 256

#define W_BLOCKS 2048
#define W_THREADS 256
#define RANGE 3908                // floats per block; 2048*3908 >= 8000064; mult of 4

// K1: dot products. One wave per 2 tokens; coalesced float4 loads; butterfly
// reduce; lane 0 writes relu((h·W+b)*mask) into ws[token].
__global__ __launch_bounds__(D_THREADS) void k1_dot(
    const float* __restrict__ hidden,   // [TOKENS, H]
    const float* __restrict__ mask,     // [TOKENS]
    const float* __restrict__ W,        // [H]
    const float* __restrict__ bias,     // [1]
    float* __restrict__ tw_ws)          // [TOKENS]
{
    const int tid = blockIdx.x * D_THREADS + threadIdx.x;
    const int lane = threadIdx.x & 63;
    const int wave = tid >> 6;          // 0..8191

    const float4* __restrict__ w4 = reinterpret_cast<const float4*>(W);
    const float bias0 = bias[0];

    const float4* __restrict__ h4a =
        reinterpret_cast<const float4*>(hidden + (size_t)(wave * 2 + 0) * HH);
    const float4* __restrict__ h4b =
        reinterpret_cast<const float4*>(hidden + (size_t)(wave * 2 + 1) * HH);

    float4 ha[4], hb[4], wv[4];
#pragma unroll
    for (int i = 0; i < 4; ++i) ha[i] = h4a[i * 64 + lane];
#pragma unroll
    for (int i = 0; i < 4; ++i) hb[i] = h4b[i * 64 + lane];
#pragma unroll
    for (int i = 0; i < 4; ++i) wv[i] = w4[i * 64 + lane];

    float sa = 0.f, sb = 0.f;
#pragma unroll
    for (int i = 0; i < 4; ++i) {
        sa = fmaf(ha[i].x, wv[i].x, sa); sa = fmaf(ha[i].y, wv[i].y, sa);
        sa = fmaf(ha[i].z, wv[i].z, sa); sa = fmaf(ha[i].w, wv[i].w, sa);
        sb = fmaf(hb[i].x, wv[i].x, sb); sb = fmaf(hb[i].y, wv[i].y, sb);
        sb = fmaf(hb[i].z, wv[i].z, sb); sb = fmaf(hb[i].w, wv[i].w, sb);
    }
#pragma unroll
    for (int off = 32; off > 0; off >>= 1) {
        sa += __shfl_xor(sa, off, 64);
        sb += __shfl_xor(sb, off, 64);
    }

    if (lane == 0) {
        const int t0 = wave * 2;
        tw_ws[t0]     = fmaxf((sa + bias0) * mask[t0], 0.0f);
        tw_ws[t0 + 1] = fmaxf((sb + bias0) * mask[t0 + 1], 0.0f);
    }
}

// K2: each block OWNS flat out range [blk*RANGE, blk*RANGE+RANGE). It zeroes
// the range (cacheable stores -> L2/L3 can absorb across replays), fences,
// then scans the token rows overlapping its range and atomicAdds in-range
// weights. Zero->add ordering is intra-block, so no kernel boundary needed.
__global__ __launch_bounds__(W_THREADS) void k2_zero_scatter(
    const float* __restrict__ tw_ws,    // [TOKENS]
    const int* __restrict__ ids,        // [TOKENS]
    float* __restrict__ out)            // [B*V]
{
    const int start = blockIdx.x * RANGE;
    const int end = min(start + RANGE, OUT_FLOATS);
    if (start >= OUT_FLOATS) return;

    // Zero own range with float4 (start is 16B-aligned: RANGE*4 % 16 == 0).
    float4* __restrict__ o4 = reinterpret_cast<float4*>(out + start);
    const int n4 = (end - start) / 4;   // RANGE/4 except possibly last block
    const float4 z = make_float4(0.f, 0.f, 0.f, 0.f);
    for (int i = threadIdx.x; i < n4; i += W_THREADS)
        o4[i] = z;
    // Tail floats (only possible in the very last block).
    for (int i = start + n4 * 4 + threadIdx.x; i < end; i += W_THREADS)
        out[i] = 0.0f;

    __threadfence();      // drain this thread's stores to L2 (coherence point)
    __syncthreads();      // all zeros of this range are now visible

    // Scan tokens of the batch rows overlapping [start, end).
    const int r0 = start / VV;
    const int r1 = (end - 1) / VV;
    for (int r = r0; r <= r1; ++r) {
        const int tbase = r * SS;
        const int rowbase = r * VV;
        for (int j = threadIdx.x; j < SS; j += W_THREADS) {
            const float w = tw_ws[tbase + j];
            if (w != 0.0f) {
                const int floc = rowbase + ids[tbase + j];
                if (floc >= start && floc < end)
                    atomicAdd(&out[floc], w);
            }
        }
    }
}

extern "C" void kernel_launch(void* const* d_in, const int* in_sizes, int n_in,
                              void* d_out, int out_size, void* d_ws, size_t ws_size,
                              hipStream_t stream) {
    const float* hidden = (const float*)d_in[0];
    const int*   ids    = (const int*)d_in[1];
    const float* mask   = (const float*)d_in[2];
    const float* W      = (const float*)d_in[3];
    const float* bias   = (const float*)d_in[4];
    float* out   = (float*)d_out;
    float* tw_ws = (float*)d_ws;        // 16384 floats

    k1_dot<<<D_BLOCKS, D_THREADS, 0, stream>>>(hidden, mask, W, bias, tw_ws);
    k2_zero_scatter<<<W_BLOCKS, W_THREADS, 0, stream>>>(tw_ws, ids, out);
}

// Round 7
// 23.712 us; speedup vs baseline: 9.6893x; 9.6893x over previous
//
#include <hip/hip_runtime.h>
#include <hip/hip_bf16.h>

// Problem constants (SparseEmbeddingHead): B=32, S=512, H=1024, V=250002
#define BB 32
#define SS 512
#define HH 1024
#define VV 250002
#define TOKENS (BB * SS)          // 16384
#define OUT_FLOATS (BB * VV)      // 8000064 (divisible by 4)

#define D_BLOCKS 2048
#define D_THREADS 256

#define W_BLOCKS 2048
#define W_THREADS 256
#define RANGE 3908                // floats per block; 2048*3908 >= 8000064; mult of 4

// K1: dot products. One wave per 2 tokens; coalesced float4 loads; butterfly
// reduce; lane 0 writes relu((h·W+b)*mask) into ws[token]. Pure read stream.
__global__ __launch_bounds__(D_THREADS) void k1_dot(
    const float* __restrict__ hidden,   // [TOKENS, H]
    const float* __restrict__ mask,     // [TOKENS]
    const float* __restrict__ W,        // [H]
    const float* __restrict__ bias,     // [1]
    float* __restrict__ tw_ws)          // [TOKENS]
{
    const int tid = blockIdx.x * D_THREADS + threadIdx.x;
    const int lane = threadIdx.x & 63;
    const int wave = tid >> 6;          // 0..8191

    const float4* __restrict__ w4 = reinterpret_cast<const float4*>(W);
    const float bias0 = bias[0];

    const float4* __restrict__ h4a =
        reinterpret_cast<const float4*>(hidden + (size_t)(wave * 2 + 0) * HH);
    const float4* __restrict__ h4b =
        reinterpret_cast<const float4*>(hidden + (size_t)(wave * 2 + 1) * HH);

    float4 ha[4], hb[4], wv[4];
#pragma unroll
    for (int i = 0; i < 4; ++i) ha[i] = h4a[i * 64 + lane];
#pragma unroll
    for (int i = 0; i < 4; ++i) hb[i] = h4b[i * 64 + lane];
#pragma unroll
    for (int i = 0; i < 4; ++i) wv[i] = w4[i * 64 + lane];

    float sa = 0.f, sb = 0.f;
#pragma unroll
    for (int i = 0; i < 4; ++i) {
        sa = fmaf(ha[i].x, wv[i].x, sa); sa = fmaf(ha[i].y, wv[i].y, sa);
        sa = fmaf(ha[i].z, wv[i].z, sa); sa = fmaf(ha[i].w, wv[i].w, sa);
        sb = fmaf(hb[i].x, wv[i].x, sb); sb = fmaf(hb[i].y, wv[i].y, sb);
        sb = fmaf(hb[i].z, wv[i].z, sb); sb = fmaf(hb[i].w, wv[i].w, sb);
    }
#pragma unroll
    for (int off = 32; off > 0; off >>= 1) {
        sa += __shfl_xor(sa, off, 64);
        sb += __shfl_xor(sb, off, 64);
    }

    if (lane == 0) {
        const int t0 = wave * 2;
        tw_ws[t0]     = fmaxf((sa + bias0) * mask[t0], 0.0f);
        tw_ws[t0 + 1] = fmaxf((sb + bias0) * mask[t0 + 1], 0.0f);
    }
}

// K2: each block OWNS flat out range [blk*RANGE, blk*RANGE+RANGE). It zeroes
// the range, syncs (workgroup scope is sufficient — only THIS block touches
// the range, and both the stores and the atomics resolve in the same L2),
// then scans the 1-2 token rows overlapping its range and atomicAdds the
// in-range weights. NO device-scope fence — that forces an L2 invalidate.
__global__ __launch_bounds__(W_THREADS) void k2_zero_scatter(
    const float* __restrict__ tw_ws,    // [TOKENS]
    const int* __restrict__ ids,        // [TOKENS]
    float* __restrict__ out)            // [B*V]
{
    const int start = blockIdx.x * RANGE;
    const int end = min(start + RANGE, OUT_FLOATS);
    if (start >= OUT_FLOATS) return;

    // Zero own range with float4 (start is 16B-aligned: RANGE*4 % 16 == 0).
    float4* __restrict__ o4 = reinterpret_cast<float4*>(out + start);
    const int n4 = (end - start) / 4;
    const float4 z = make_float4(0.f, 0.f, 0.f, 0.f);
    for (int i = threadIdx.x; i < n4; i += W_THREADS)
        o4[i] = z;
    for (int i = start + n4 * 4 + threadIdx.x; i < end; i += W_THREADS)
        out[i] = 0.0f;

    __threadfence_block();  // waitcnt only — no L2 invalidate
    __syncthreads();        // zeros visible block-wide (same L2)

    // Scan tokens of the batch rows overlapping [start, end).
    const int r0 = start / VV;
    const int r1 = (end - 1) / VV;
    for (int r = r0; r <= r1; ++r) {
        const int tbase = r * SS;
        const int rowbase = r * VV;
        for (int j = threadIdx.x; j < SS; j += W_THREADS) {
            const float w = tw_ws[tbase + j];
            if (w != 0.0f) {
                const int floc = rowbase + ids[tbase + j];
                if (floc >= start && floc < end)
                    atomicAdd(&out[floc], w);
            }
        }
    }
}

extern "C" void kernel_launch(void* const* d_in, const int* in_sizes, int n_in,
                              void* d_out, int out_size, void* d_ws, size_t ws_size,
                              hipStream_t stream) {
    const float* hidden = (const float*)d_in[0];
    const int*   ids    = (const int*)d_in[1];
    const float* mask   = (const float*)d_in[2];
    const float* W      = (const float*)d_in[3];
    const float* bias   = (const float*)d_in[4];
    float* out   = (float*)d_out;
    float* tw_ws = (float*)d_ws;        // 16384 floats

    k1_dot<<<D_BLOCKS, D_THREADS, 0, stream>>>(hidden, mask, W, bias, tw_ws);
    k2_zero_scatter<<<W_BLOCKS, W_THREADS, 0, stream>>>(tw_ws, ids, out);
}

// Round 8
// 21.765 us; speedup vs baseline: 10.5560x; 1.0894x over previous
//
#include <hip/hip_runtime.h>
#include <hip/hip_bf16.h>

// Problem constants (SparseEmbeddingHead): B=32, S=512, H=1024, V=250002
#define BB 32
#define SS 512
#define HH 1024
#define VV 250002
#define TOKENS (BB * SS)          // 16384
#define OUT_FLOATS (BB * VV)      // 8000064 (divisible by 4)
#define OUT_F4 (OUT_FLOATS / 4)   // 2000016

#define K1_BLOCKS 2048
#define K1_THREADS 256
#define K1_TID (K1_BLOCKS * K1_THREADS)

// K1: fused zero + dot. Loads for 2 tokens (8x float4) issue FIRST, then the
// zero-store burst runs under their latency, then FMA+reduce consumes them.
// Zero uses CACHEABLE stores so L2/L3 can absorb the 32 MB write stream
// (out is rewritten every replay and read by nobody until validation).
__global__ __launch_bounds__(K1_THREADS) void k1_zero_and_dot(
    const float* __restrict__ hidden,   // [TOKENS, H]
    const float* __restrict__ mask,     // [TOKENS]
    const float* __restrict__ W,        // [H]
    const float* __restrict__ bias,     // [1]
    float* __restrict__ out,            // [B*V] — zeroed here
    float* __restrict__ tw_ws)          // [TOKENS]
{
    const int tid = blockIdx.x * K1_THREADS + threadIdx.x;
    const int lane = threadIdx.x & 63;
    const int wave = tid >> 6;          // 0..8191  (2 tokens each)

    const float4* __restrict__ w4 = reinterpret_cast<const float4*>(W);
    const float4* __restrict__ h4a =
        reinterpret_cast<const float4*>(hidden + (size_t)(wave * 2 + 0) * HH);
    const float4* __restrict__ h4b =
        reinterpret_cast<const float4*>(hidden + (size_t)(wave * 2 + 1) * HH);

    // Issue all 12 loads up-front (8 hidden from HBM + 4 W from L1/L2).
    float4 ha[4], hb[4], wv[4];
#pragma unroll
    for (int i = 0; i < 4; ++i) ha[i] = h4a[i * 64 + lane];
#pragma unroll
    for (int i = 0; i < 4; ++i) hb[i] = h4b[i * 64 + lane];
#pragma unroll
    for (int i = 0; i < 4; ++i) wv[i] = w4[i * 64 + lane];

    // Zero-store burst while the loads are in flight (independent stream).
    float4* __restrict__ o4 = reinterpret_cast<float4*>(out);
    const float4 z = make_float4(0.f, 0.f, 0.f, 0.f);
    for (int i = tid; i < OUT_F4; i += K1_TID)
        o4[i] = z;

    // Consume loads.
    float sa = 0.f, sb = 0.f;
#pragma unroll
    for (int i = 0; i < 4; ++i) {
        sa = fmaf(ha[i].x, wv[i].x, sa); sa = fmaf(ha[i].y, wv[i].y, sa);
        sa = fmaf(ha[i].z, wv[i].z, sa); sa = fmaf(ha[i].w, wv[i].w, sa);
        sb = fmaf(hb[i].x, wv[i].x, sb); sb = fmaf(hb[i].y, wv[i].y, sb);
        sb = fmaf(hb[i].z, wv[i].z, sb); sb = fmaf(hb[i].w, wv[i].w, sb);
    }
#pragma unroll
    for (int off = 32; off > 0; off >>= 1) {
        sa += __shfl_xor(sa, off, 64);
        sb += __shfl_xor(sb, off, 64);
    }

    if (lane == 0) {
        const int t0 = wave * 2;
        const float bias0 = bias[0];
        tw_ws[t0]     = fmaxf((sa + bias0) * mask[t0], 0.0f);
        tw_ws[t0 + 1] = fmaxf((sb + bias0) * mask[t0 + 1], 0.0f);
    }
}

// K2: scatter the 16384 token weights into out (runs after k1, stream order).
__global__ __launch_bounds__(256) void k2_scatter(
    const float* __restrict__ tw_ws,    // [TOKENS]
    const int* __restrict__ ids,        // [TOKENS]
    float* __restrict__ out)            // [B*V]
{
    const int t = blockIdx.x * 256 + threadIdx.x;
    if (t >= TOKENS) return;
    const float tw = tw_ws[t];
    if (tw != 0.0f)
        atomicAdd(&out[(size_t)(t / SS) * VV + ids[t]], tw);
}

extern "C" void kernel_launch(void* const* d_in, const int* in_sizes, int n_in,
                              void* d_out, int out_size, void* d_ws, size_t ws_size,
                              hipStream_t stream) {
    const float* hidden = (const float*)d_in[0];
    const int*   ids    = (const int*)d_in[1];
    const float* mask   = (const float*)d_in[2];
    const float* W      = (const float*)d_in[3];
    const float* bias   = (const float*)d_in[4];
    float* out   = (float*)d_out;
    float* tw_ws = (float*)d_ws;        // 16384 floats

    k1_zero_and_dot<<<K1_BLOCKS, K1_THREADS, 0, stream>>>(hidden, mask, W, bias, out, tw_ws);
    k2_scatter<<<(TOKENS + 255) / 256, 256, 0, stream>>>(tw_ws, ids, out);
}

// Round 9
// 21.333 us; speedup vs baseline: 10.7695x; 1.0202x over previous
//
#include <hip/hip_runtime.h>
#include <hip/hip_bf16.h>

// Problem constants (SparseEmbeddingHead): B=32, S=512, H=1024, V=250002
#define BB 32
#define SS 512
#define HH 1024
#define VV 250002
#define TOKENS (BB * SS)          // 16384
#define OUT_FLOATS (BB * VV)      // 8000064 (divisible by 4)
#define OUT_F4 (OUT_FLOATS / 4)   // 2000016

#define K1_BLOCKS 1024
#define K1_THREADS 256
#define Z_PER_THREAD 8            // 1024*256*8 = 2097152 >= 2000016

// K1: fused zero + dot. 4 tokens per wave (4096 waves, 1024 blocks).
// All broadcast operands (bias, mask4, W) load FIRST, then 16 hidden float4
// loads issue, then the block-contiguous zero-store burst runs under their
// latency, then FMA + butterfly reduce consumes.
__global__ __launch_bounds__(K1_THREADS) void k1_zero_and_dot(
    const float* __restrict__ hidden,   // [TOKENS, H]
    const float* __restrict__ mask,     // [TOKENS]
    const float* __restrict__ W,        // [H]
    const float* __restrict__ bias,     // [1]
    float* __restrict__ out,            // [B*V] — zeroed here
    float* __restrict__ tw_ws)          // [TOKENS]
{
    const int tid = blockIdx.x * K1_THREADS + threadIdx.x;
    const int lane = threadIdx.x & 63;
    const int wave = tid >> 6;          // 0..4095
    const int t0 = wave * 4;            // 4 tokens per wave, 16B-aligned

    // Broadcast loads first (L1/L2-resident after first touch).
    const float bias0 = bias[0];
    const float4 m4 = *reinterpret_cast<const float4*>(mask + t0);

    const float4* __restrict__ w4 = reinterpret_cast<const float4*>(W);
    float4 wv[4];
#pragma unroll
    for (int i = 0; i < 4; ++i) wv[i] = w4[i * 64 + lane];

    // Issue 16 hidden loads (4 tokens x 4 float4/lane).
    float4 h[4][4];
#pragma unroll
    for (int tt = 0; tt < 4; ++tt) {
        const float4* __restrict__ h4 =
            reinterpret_cast<const float4*>(hidden + (size_t)(t0 + tt) * HH);
#pragma unroll
        for (int i = 0; i < 4; ++i) h[tt][i] = h4[i * 64 + lane];
    }

    // Zero-store burst while loads are in flight (block-contiguous slice).
    {
        float4* __restrict__ o4 = reinterpret_cast<float4*>(out);
        const float4 z = make_float4(0.f, 0.f, 0.f, 0.f);
        const int base = blockIdx.x * (K1_THREADS * Z_PER_THREAD) + threadIdx.x;
#pragma unroll
        for (int k = 0; k < Z_PER_THREAD; ++k) {
            const int i = base + k * K1_THREADS;
            if (i < OUT_F4) o4[i] = z;
        }
    }

    // Consume loads.
    float s[4] = {0.f, 0.f, 0.f, 0.f};
#pragma unroll
    for (int tt = 0; tt < 4; ++tt)
#pragma unroll
        for (int i = 0; i < 4; ++i) {
            s[tt] = fmaf(h[tt][i].x, wv[i].x, s[tt]);
            s[tt] = fmaf(h[tt][i].y, wv[i].y, s[tt]);
            s[tt] = fmaf(h[tt][i].z, wv[i].z, s[tt]);
            s[tt] = fmaf(h[tt][i].w, wv[i].w, s[tt]);
        }

#pragma unroll
    for (int off = 32; off > 0; off >>= 1) {
#pragma unroll
        for (int tt = 0; tt < 4; ++tt)
            s[tt] += __shfl_xor(s[tt], off, 64);
    }

    if (lane == 0) {
        float4 r;
        r.x = fmaxf((s[0] + bias0) * m4.x, 0.0f);
        r.y = fmaxf((s[1] + bias0) * m4.y, 0.0f);
        r.z = fmaxf((s[2] + bias0) * m4.z, 0.0f);
        r.w = fmaxf((s[3] + bias0) * m4.w, 0.0f);
        *reinterpret_cast<float4*>(tw_ws + t0) = r;
    }
}

// K2: scatter the 16384 token weights into out (runs after k1, stream order).
__global__ __launch_bounds__(256) void k2_scatter(
    const float* __restrict__ tw_ws,    // [TOKENS]
    const int* __restrict__ ids,        // [TOKENS]
    float* __restrict__ out)            // [B*V]
{
    const int t = blockIdx.x * 256 + threadIdx.x;
    if (t >= TOKENS) return;
    const float tw = tw_ws[t];
    if (tw != 0.0f)
        atomicAdd(&out[(size_t)(t / SS) * VV + ids[t]], tw);
}

extern "C" void kernel_launch(void* const* d_in, const int* in_sizes, int n_in,
                              void* d_out, int out_size, void* d_ws, size_t ws_size,
                              hipStream_t stream) {
    const float* hidden = (const float*)d_in[0];
    const int*   ids    = (const int*)d_in[1];
    const float* mask   = (const float*)d_in[2];
    const float* W      = (const float*)d_in[3];
    const float* bias   = (const float*)d_in[4];
    float* out   = (float*)d_out;
    float* tw_ws = (float*)d_ws;        // 16384 floats

    k1_zero_and_dot<<<K1_BLOCKS, K1_THREADS, 0, stream>>>(hidden, mask, W, bias, out, tw_ws);
    k2_scatter<<<(TOKENS + 255) / 256, 256, 0, stream>>>(tw_ws, ids, out);
}